// Round 2
// baseline (26.083 us; speedup 1.0000x reference)
//
#include <hip/hip_runtime.h>

// RoPE: out[..., 2j]   = cos(a)*x[...,2j] - sin(a)*x[...,2j+1]
//       out[..., 2j+1] = sin(a)*x[...,2j] + cos(a)*x[...,2j+1]
// a = pos * theta^(-2j/d_k),  d_k = 128, theta = 10000.
//
// Memory-bound (129 MB traffic, ~20.5 us HBM floor). One thread = one float4
// = 2 pairs. Grid-stride stride is a multiple of 32 float4s/row so the
// per-thread frequency exp2s hoist out of the loop.
//
// Trig via v_sin_f32/v_cos_f32 (input in REVOLUTIONS): fold 1/(2*pi) into the
// frequency constant, range-reduce with v_fract_f32. rev >= 0 always.
// NOTE: __exp2f/__sincosf clash with glibc math.h in the host pass — use
// exp2f + __builtin_amdgcn_* instead.

constexpr float LOG2_THETA = 13.28771237954945f;  // log2(10000)
constexpr float LOG2_2PI   = 2.6514961294723187f; // log2(2*pi)

__global__ __launch_bounds__(256)
void rope_f32_kernel(const float* __restrict__ x,
                     const int* __restrict__ pos,
                     float* __restrict__ out,
                     int n_vec4) {
    const int stride = gridDim.x * blockDim.x;
    const int i0 = blockIdx.x * blockDim.x + threadIdx.x;

    // q = float4 index within the 128-wide row: constant across grid-stride
    // iterations because stride % 32 == 0.
    const int q = i0 & 31;
    const int j0 = 2 * q;  // first pair index covered by this float4
    // f[j] = theta^(-2j/128) / (2*pi) = exp2(-(2j)*log2(theta)/128 - log2(2pi))
    const float f0 = exp2f(-(float)(2 * j0)       * (LOG2_THETA / 128.0f) - LOG2_2PI);
    const float f1 = exp2f(-(float)(2 * (j0 + 1)) * (LOG2_THETA / 128.0f) - LOG2_2PI);

    const float4* __restrict__ xv = reinterpret_cast<const float4*>(x);
    float4* __restrict__ ov = reinterpret_cast<float4*>(out);

    for (int i = i0; i < n_vec4; i += stride) {
        const float4 v = xv[i];
        const int row = i >> 5;  // 32 float4 per d_k=128 row
        const float p = (float)pos[row];

        const float r0 = __builtin_amdgcn_fractf(p * f0);  // revolutions in [0,1)
        const float r1 = __builtin_amdgcn_fractf(p * f1);
        const float s0 = __builtin_amdgcn_sinf(r0);  // sin(2*pi*r0) = sin(angle0)
        const float c0 = __builtin_amdgcn_cosf(r0);
        const float s1 = __builtin_amdgcn_sinf(r1);
        const float c1 = __builtin_amdgcn_cosf(r1);

        float4 r;
        r.x = c0 * v.x - s0 * v.y;
        r.y = s0 * v.x + c0 * v.y;
        r.z = c1 * v.z - s1 * v.w;
        r.w = s1 * v.z + c1 * v.w;
        ov[i] = r;
    }
}

extern "C" void kernel_launch(void* const* d_in, const int* in_sizes, int n_in,
                              void* d_out, int out_size, void* d_ws, size_t ws_size,
                              hipStream_t stream) {
    const float* x = (const float*)d_in[0];
    const int* pos = (const int*)d_in[1];
    float* out = (float*)d_out;

    const int n = in_sizes[0];  // B*S*DK = 16*8192*128
    const int n_vec4 = n / 4;   // 4,194,304

    const int block = 256;
    int grid = (n_vec4 + block - 1) / block;
    if (grid > 2048) grid = 2048;  // grid-stride; stride % 32 == 0 holds

    rope_f32_kernel<<<grid, block, 0, stream>>>(x, pos, out, n_vec4);
}